// Round 2
// baseline (507.364 us; speedup 1.0000x reference)
//
#include <hip/hip_runtime.h>
#include <stdint.h>

#define B_ 16
#define C_ 512
#define N_ 4096
#define K_ 64
#define NUM_STAGES 3

typedef __bf16 bf16x8 __attribute__((ext_vector_type(8)));
typedef float f32x4 __attribute__((ext_vector_type(4)));

__device__ __forceinline__ uint16_t f2bf(float x) {
  union { float f; uint32_t u; } v; v.f = x;
  uint32_t r = (v.u + 0x7FFFu + ((v.u >> 16) & 1u)) >> 16;
  return (uint16_t)r;
}

__device__ __forceinline__ void async16(const uint16_t* g, uint16_t* l) {
  __builtin_amdgcn_global_load_lds(
      (const __attribute__((address_space(1))) unsigned int*)g,
      (__attribute__((address_space(3))) unsigned int*)l, 16, 0, 0);
}

// ---------------- prep: fp32 feats -> bf16 f [B][C][N] and fT [B][N][C] ----
// 64c x 256n per block (4 sub-tiles), vectorized LDS stores.
__global__ __launch_bounds__(256) void k_prep(const float* __restrict__ feats,
                                              uint16_t* __restrict__ f16,
                                              uint16_t* __restrict__ fT16) {
  __shared__ uint16_t tile[64][68];
  int b = blockIdx.z, c0 = blockIdx.y * 64, n0 = blockIdx.x * 256;
  int t = threadIdx.x;
  int cl = t >> 4;          // 0..15
  int nl = (t & 15) * 4;    // 0..60
  for (int nt = 0; nt < 4; ++nt) {
    int n0s = n0 + nt * 64;
    const float* src = feats + ((size_t)b * C_ + c0) * N_ + n0s;
    uint16_t* dst = f16 + ((size_t)b * C_ + c0) * N_ + n0s;
    __syncthreads();
#pragma unroll
    for (int i = 0; i < 4; ++i) {
      int c = cl + 16 * i;
      float4 v = *(const float4*)(src + (size_t)c * N_ + nl);
      ushort4 x;
      x.x = f2bf(v.x); x.y = f2bf(v.y); x.z = f2bf(v.z); x.w = f2bf(v.w);
      *(ushort4*)(dst + (size_t)c * N_ + nl) = x;
      *(ushort4*)&tile[c][nl] = x;
    }
    __syncthreads();
    uint16_t* dstT = fT16 + ((size_t)b * N_ + n0s) * C_ + c0;
#pragma unroll
    for (int i = 0; i < 4; ++i) {
      int n = cl + 16 * i;
      int c = nl;
      ushort4 y;
      y.x = tile[c + 0][n]; y.y = tile[c + 1][n];
      y.z = tile[c + 2][n]; y.w = tile[c + 3][n];
      *(ushort4*)(dstT + (size_t)n * C_ + c) = y;
    }
  }
}

// ---------------- init: l2norm(bases over C) -> basis [B][C][K], basisT [B][K][C]
__global__ __launch_bounds__(256) void k_init_basis(const float* __restrict__ bases,
                                                    uint16_t* __restrict__ basis,
                                                    uint16_t* __restrict__ basisT) {
  int b = blockIdx.x;
  int t = threadIdx.x;
  __shared__ float red[256];
  __shared__ float inv[64];
  int k = t & 63;
  float s = 0.f;
  for (int c = (t >> 6); c < C_; c += 4) {
    float v = bases[c * K_ + k];
    s += v * v;
  }
  red[t] = s;
  __syncthreads();
  if (t < 64) {
    float tot = red[t] + red[t + 64] + red[t + 128] + red[t + 192];
    inv[t] = 1.f / (1e-6f + sqrtf(tot));
  }
  __syncthreads();
  uint16_t* ob = basis + (size_t)b * C_ * K_;
  for (int i = 0; i < (C_ * K_) / 256; ++i) {
    int idx = t + 256 * i;
    int kk = idx & 63;
    ob[idx] = f2bf(bases[idx] * inv[kk]);
  }
  uint16_t* obT = basisT + (size_t)b * K_ * C_;
  for (int i = 0; i < (C_ * K_) / 256; ++i) {
    int idx = t + 256 * i;
    int kk = idx >> 9;
    int cc = idx & 511;
    obT[idx] = f2bf(bases[cc * K_ + kk] * inv[kk]);
  }
}

// ---------------- GEMM1 + fused softmax: attn[b,n,k] = softmax_k( sum_c fT[n,c]*basisT[k,c] )
// 128n x 64k per block, 512 threads (8 waves, wave w owns n in [16w,16w+16))
__global__ __launch_bounds__(512) void k_gemm1(const uint16_t* __restrict__ fT,
                                               const uint16_t* __restrict__ basisT,
                                               uint16_t* __restrict__ attn,    // [B][N][K]
                                               uint16_t* __restrict__ attnT,   // [B][K][N]
                                               int write_attn) {
  __shared__ __attribute__((aligned(16))) uint16_t ldsA[128 * 64]; // 16 KB
  __shared__ __attribute__((aligned(16))) uint16_t ldsB[64 * 64];  // 8 KB
  int b = blockIdx.y;
  int n0 = blockIdx.x * 128;
  int t = threadIdx.x;
  int w = t >> 6, lane = t & 63, l15 = lane & 15, quad = lane >> 4;
  const uint16_t* A = fT + ((size_t)b * N_ + n0) * C_;
  const uint16_t* Bm = basisT + (size_t)b * K_ * C_;
  f32x4 acc[4] = {};
  for (int cs = 0; cs < C_; cs += 64) {
    __syncthreads();
#pragma unroll
    for (int r = 0; r < 2; ++r) {
      int e = r * 512 + t;
      int row = e >> 3, ch = e & 7;
      int sch = (ch + row) & 7;
      async16(A + (size_t)row * C_ + cs + sch * 8, ldsA + (r * 512 + (t & 448)) * 8);
    }
    {
      int row = t >> 3, ch = t & 7;
      int sch = (ch + row) & 7;
      async16(Bm + (size_t)row * C_ + cs + sch * 8, ldsB + (t & 448) * 8);
    }
    __syncthreads();
#pragma unroll
    for (int s = 0; s < 2; ++s) {
      int cc = s * 4 + quad;
      int ra = 16 * w + l15;
      bf16x8 af = *(const bf16x8*)(ldsA + ra * 64 + ((cc - ra) & 7) * 8);
#pragma unroll
      for (int t4 = 0; t4 < 4; ++t4) {
        int rb = 16 * t4 + l15;
        bf16x8 bv = *(const bf16x8*)(ldsB + rb * 64 + ((cc - rb) & 7) * 8);
        acc[t4] = __builtin_amdgcn_mfma_f32_16x16x32_bf16(af, bv, acc[t4], 0, 0, 0);
      }
    }
  }
  // fused softmax over k=64; row n = n0 + 16w + quad*4 + r, k = 16*t4 + l15
  float p[4][4];
#pragma unroll
  for (int r = 0; r < 4; ++r) {
    float m = fmaxf(fmaxf(acc[0][r], acc[1][r]), fmaxf(acc[2][r], acc[3][r]));
    m = fmaxf(m, __shfl_xor(m, 1));
    m = fmaxf(m, __shfl_xor(m, 2));
    m = fmaxf(m, __shfl_xor(m, 4));
    m = fmaxf(m, __shfl_xor(m, 8));
    float s = 0.f;
#pragma unroll
    for (int t4 = 0; t4 < 4; ++t4) { p[t4][r] = __expf(acc[t4][r] - m); s += p[t4][r]; }
    s += __shfl_xor(s, 1); s += __shfl_xor(s, 2);
    s += __shfl_xor(s, 4); s += __shfl_xor(s, 8);
    float inv = 1.f / s;
#pragma unroll
    for (int t4 = 0; t4 < 4; ++t4) p[t4][r] *= inv;
  }
  if (write_attn) {
    uint16_t* oa = attn + ((size_t)b * N_ + n0 + 16 * w + quad * 4) * K_;
#pragma unroll
    for (int r = 0; r < 4; ++r) {
#pragma unroll
      for (int t4 = 0; t4 < 4; ++t4) oa[(size_t)r * K_ + 16 * t4 + l15] = f2bf(p[t4][r]);
    }
  }
#pragma unroll
  for (int t4 = 0; t4 < 4; ++t4) {
    ushort4 y;
    y.x = f2bf(p[t4][0]); y.y = f2bf(p[t4][1]);
    y.z = f2bf(p[t4][2]); y.w = f2bf(p[t4][3]);
    *(ushort4*)(attnT + ((size_t)b * K_ + 16 * t4 + l15) * N_ + n0 + 16 * w + quad * 4) = y;
  }
}

// ---------------- GEMM2 (split-K=8): brawT[s][b][k][c] = sum_{n in slice} attnT[k,n]*f[c,n]
// 64k x 128c per block, 512 threads (wave w owns c in [16w,16w+16))
__global__ __launch_bounds__(512) void k_gemm2(const uint16_t* __restrict__ f16,
                                               const uint16_t* __restrict__ attnT,
                                               float* __restrict__ brawT) {
  __shared__ __attribute__((aligned(16))) uint16_t ldsF[128 * 64]; // c-rows x n, 16 KB
  __shared__ __attribute__((aligned(16))) uint16_t ldsP[64 * 64];  // k-rows x n, 8 KB
  int b = blockIdx.z;
  int slice = blockIdx.y;
  int c0 = blockIdx.x * 128;
  int t = threadIdx.x;
  int w = t >> 6, lane = t & 63, l15 = lane & 15, quad = lane >> 4;
  const uint16_t* F = f16 + ((size_t)b * C_ + c0) * N_;
  const uint16_t* P = attnT + (size_t)b * K_ * N_;
  f32x4 acc[4] = {};
  int ns0 = slice * 512;
  for (int ns = ns0; ns < ns0 + 512; ns += 64) {
    __syncthreads();
#pragma unroll
    for (int r = 0; r < 2; ++r) {
      int e = r * 512 + t;
      int row = e >> 3, ch = e & 7;
      int sch = (ch + row) & 7;
      async16(F + (size_t)row * N_ + ns + sch * 8, ldsF + (r * 512 + (t & 448)) * 8);
    }
    {
      int row = t >> 3, ch = t & 7;
      int sch = (ch + row) & 7;
      async16(P + (size_t)row * N_ + ns + sch * 8, ldsP + (t & 448) * 8);
    }
    __syncthreads();
#pragma unroll
    for (int s = 0; s < 2; ++s) {
      int cc = s * 4 + quad;
      int rb = 16 * w + l15;
      bf16x8 fv = *(const bf16x8*)(ldsF + rb * 64 + ((cc - rb) & 7) * 8);
#pragma unroll
      for (int kt = 0; kt < 4; ++kt) {
        int ra = 16 * kt + l15;
        bf16x8 av = *(const bf16x8*)(ldsP + ra * 64 + ((cc - ra) & 7) * 8);
        acc[kt] = __builtin_amdgcn_mfma_f32_16x16x32_bf16(av, fv, acc[kt], 0, 0, 0);
      }
    }
  }
  // D[m=k][col=c]: c = c0 + 16w + l15, k = 16kt + quad*4 + r
  float* outp = brawT + ((size_t)slice * B_ + b) * K_ * C_;
#pragma unroll
  for (int kt = 0; kt < 4; ++kt) {
#pragma unroll
    for (int r = 0; r < 4; ++r) {
      outp[(size_t)(16 * kt + quad * 4 + r) * C_ + c0 + 16 * w + l15] = acc[kt][r];
    }
  }
}

// ---------------- l2norm of b columns (over C), summing 8 split slices
__global__ __launch_bounds__(256) void k_l2norm(const float* __restrict__ brawT,
                                                uint16_t* __restrict__ basisT) {
  int b = blockIdx.x;
  int t = threadIdx.x, w = t >> 6, lane = t & 63;
  for (int k = w; k < K_; k += 4) {
    float v[8];
#pragma unroll
    for (int j = 0; j < 8; ++j) v[j] = 0.f;
#pragma unroll
    for (int s = 0; s < 8; ++s) {
      const float* rs = brawT + (((size_t)s * B_ + b) * K_ + k) * C_ + lane * 8;
      float4 a = *(const float4*)(rs);
      float4 c4 = *(const float4*)(rs + 4);
      v[0] += a.x; v[1] += a.y; v[2] += a.z; v[3] += a.w;
      v[4] += c4.x; v[5] += c4.y; v[6] += c4.z; v[7] += c4.w;
    }
    float ss = 0.f;
#pragma unroll
    for (int j = 0; j < 8; ++j) ss += v[j] * v[j];
    ss += __shfl_xor(ss, 1); ss += __shfl_xor(ss, 2); ss += __shfl_xor(ss, 4);
    ss += __shfl_xor(ss, 8); ss += __shfl_xor(ss, 16); ss += __shfl_xor(ss, 32);
    float inv = 1.f / (1e-6f + sqrtf(ss));
    ushort4 y0, y1;
    y0.x = f2bf(v[0] * inv); y0.y = f2bf(v[1] * inv);
    y0.z = f2bf(v[2] * inv); y0.w = f2bf(v[3] * inv);
    y1.x = f2bf(v[4] * inv); y1.y = f2bf(v[5] * inv);
    y1.z = f2bf(v[6] * inv); y1.w = f2bf(v[7] * inv);
    uint16_t* o = basisT + ((size_t)b * K_ + k) * C_ + lane * 8;
    *(ushort4*)(o) = y0;
    *(ushort4*)(o + 4) = y1;
  }
}

// ---------------- transpose basisT -> basis [B][C][K]
__global__ __launch_bounds__(256) void k_transpose_basis(const uint16_t* __restrict__ basisT,
                                                         uint16_t* __restrict__ basis) {
  __shared__ uint16_t tile[64][65];
  int b = blockIdx.y, ct = blockIdx.x;
  int t = threadIdx.x;
  const uint16_t* src = basisT + (size_t)b * K_ * C_ + ct * 64;
  for (int i = 0; i < 16; ++i) {
    int idx = t + 256 * i;
    int k = idx >> 6, c = idx & 63;
    tile[k][c] = src[(size_t)k * C_ + c];
  }
  __syncthreads();
  uint16_t* dst = basis + (size_t)b * C_ * K_ + (size_t)ct * 64 * K_;
  for (int i = 0; i < 16; ++i) {
    int idx = t + 256 * i;
    int c = idx >> 6, k = idx & 63;
    dst[(size_t)c * K_ + k] = tile[k][c];
  }
}

// ---------------- recon: out[b,c,n] = sum_k basis[c,k]*attn[n,k] (fp32 out)
// 128n x 64c per block, 512 threads
__global__ __launch_bounds__(512) void k_recon(const uint16_t* __restrict__ attn,
                                               const uint16_t* __restrict__ basis,
                                               float* __restrict__ out) {
  __shared__ __attribute__((aligned(16))) uint16_t ldsA[128 * 64]; // n-rows x k
  __shared__ __attribute__((aligned(16))) uint16_t ldsB[64 * 64];  // c-rows x k
  int b = blockIdx.z, c0 = blockIdx.y * 64, n0 = blockIdx.x * 128;
  int t = threadIdx.x, w = t >> 6, lane = t & 63, l15 = lane & 15, quad = lane >> 4;
  const uint16_t* A = attn + ((size_t)b * N_ + n0) * K_;
  const uint16_t* Bm = basis + ((size_t)b * C_ + c0) * K_;
#pragma unroll
  for (int r = 0; r < 2; ++r) {
    int e = r * 512 + t;
    int row = e >> 3, ch = e & 7, sch = (ch + row) & 7;
    async16(A + (size_t)row * K_ + sch * 8, ldsA + (r * 512 + (t & 448)) * 8);
  }
  {
    int row = t >> 3, ch = t & 7, sch = (ch + row) & 7;
    async16(Bm + (size_t)row * K_ + sch * 8, ldsB + (t & 448) * 8);
  }
  f32x4 acc[4] = {};
  __syncthreads();
#pragma unroll
  for (int s = 0; s < 2; ++s) {
    int cc = s * 4 + quad;
    int ra = 16 * w + l15;
    bf16x8 af = *(const bf16x8*)(ldsA + ra * 64 + ((cc - ra) & 7) * 8);
#pragma unroll
    for (int t4 = 0; t4 < 4; ++t4) {
      int rb = 16 * t4 + l15;
      bf16x8 bv = *(const bf16x8*)(ldsB + rb * 64 + ((cc - rb) & 7) * 8);
      acc[t4] = __builtin_amdgcn_mfma_f32_16x16x32_bf16(af, bv, acc[t4], 0, 0, 0);
    }
  }
#pragma unroll
  for (int t4 = 0; t4 < 4; ++t4) {
    int c = c0 + 16 * t4 + l15;
    float4 v = make_float4(acc[t4][0], acc[t4][1], acc[t4][2], acc[t4][3]);
    *(float4*)(out + ((size_t)b * C_ + c) * N_ + n0 + 16 * w + quad * 4) = v;
  }
}

extern "C" void kernel_launch(void* const* d_in, const int* in_sizes, int n_in,
                              void* d_out, int out_size, void* d_ws, size_t ws_size,
                              hipStream_t stream) {
  const float* feats = (const float*)d_in[0];
  const float* bases = (const float*)d_in[1];
  float* out = (float*)d_out;
  char* ws = (char*)d_ws;
  uint16_t* f16 = (uint16_t*)(ws);                         // 64 MB
  uint16_t* fT16 = (uint16_t*)(ws + 67108864);             // 64 MB
  uint16_t* attn = (uint16_t*)(ws + 134217728);            // 8 MB
  uint16_t* attnT = (uint16_t*)(ws + 142606336);           // 8 MB
  uint16_t* basis = (uint16_t*)(ws + 150994944);           // 1 MB
  uint16_t* basisT = (uint16_t*)(ws + 152043520);          // 1 MB
  float* brawT = (float*)(ws + 153092096);                 // 16 MB (8 slices)

  k_prep<<<dim3(16, 8, 16), 256, 0, stream>>>(feats, f16, fT16);
  k_init_basis<<<16, 256, 0, stream>>>(bases, basis, basisT);
  for (int st = 0; st < NUM_STAGES; ++st) {
    k_gemm1<<<dim3(32, 16), 512, 0, stream>>>(fT16, basisT, attn, attnT,
                                              st == NUM_STAGES - 1 ? 1 : 0);
    k_gemm2<<<dim3(4, 8, 16), 512, 0, stream>>>(f16, attnT, brawT);
    k_l2norm<<<16, 256, 0, stream>>>(brawT, basisT);
    k_transpose_basis<<<dim3(8, 16), 256, 0, stream>>>(basisT, basis);
  }
  k_recon<<<dim3(32, 8, 16), 512, 0, stream>>>(attn, basis, out);
}

// Round 3
// 491.277 us; speedup vs baseline: 1.0327x; 1.0327x over previous
//
#include <hip/hip_runtime.h>
#include <stdint.h>

#define B_ 16
#define C_ 512
#define N_ 4096
#define K_ 64
#define NUM_STAGES 3

typedef __bf16 bf16x8 __attribute__((ext_vector_type(8)));
typedef float f32x4 __attribute__((ext_vector_type(4)));

__device__ __forceinline__ uint16_t f2bf(float x) {
  union { float f; uint32_t u; } v; v.f = x;
  uint32_t r = (v.u + 0x7FFFu + ((v.u >> 16) & 1u)) >> 16;
  return (uint16_t)r;
}

__device__ __forceinline__ void async16(const uint16_t* g, uint16_t* l) {
  __builtin_amdgcn_global_load_lds(
      (const __attribute__((address_space(1))) unsigned int*)g,
      (__attribute__((address_space(3))) unsigned int*)l, 16, 0, 0);
}

// ---------------- prep: fp32 feats -> bf16 f [B][C][N] and fT [B][N][C] ----
// (round-0 version: measured 0 bank conflicts)
__global__ __launch_bounds__(256) void k_prep(const float* __restrict__ feats,
                                              uint16_t* __restrict__ f16,
                                              uint16_t* __restrict__ fT16) {
  __shared__ uint16_t tile[64][65];
  int b = blockIdx.z, c0 = blockIdx.y * 64, n0 = blockIdx.x * 64;
  int t = threadIdx.x;
  const float* src = feats + ((size_t)b * C_ + c0) * N_ + n0;
  uint16_t* dst = f16 + ((size_t)b * C_ + c0) * N_ + n0;
  int cl = t >> 4;          // 0..15
  int nl = (t & 15) * 4;    // 0..60
#pragma unroll
  for (int i = 0; i < 4; ++i) {
    int c = cl + 16 * i;
    float4 v = *(const float4*)(src + (size_t)c * N_ + nl);
    ushort4 x;
    x.x = f2bf(v.x); x.y = f2bf(v.y); x.z = f2bf(v.z); x.w = f2bf(v.w);
    *(ushort4*)(dst + (size_t)c * N_ + nl) = x;
    tile[c][nl + 0] = x.x; tile[c][nl + 1] = x.y;
    tile[c][nl + 2] = x.z; tile[c][nl + 3] = x.w;
  }
  __syncthreads();
  uint16_t* dstT = fT16 + ((size_t)b * N_ + n0) * C_ + c0;
#pragma unroll
  for (int i = 0; i < 4; ++i) {
    int n = cl + 16 * i;
    int c = nl;
    ushort4 y;
    y.x = tile[c + 0][n]; y.y = tile[c + 1][n];
    y.z = tile[c + 2][n]; y.w = tile[c + 3][n];
    *(ushort4*)(dstT + (size_t)n * C_ + c) = y;
  }
}

// ---------------- init: l2norm(bases over C) -> basis [B][C][K], basisT [B][K][C]
__global__ __launch_bounds__(256) void k_init_basis(const float* __restrict__ bases,
                                                    uint16_t* __restrict__ basis,
                                                    uint16_t* __restrict__ basisT) {
  int b = blockIdx.x;
  int t = threadIdx.x;
  __shared__ float red[256];
  __shared__ float inv[64];
  int k = t & 63;
  float s = 0.f;
  for (int c = (t >> 6); c < C_; c += 4) {
    float v = bases[c * K_ + k];
    s += v * v;
  }
  red[t] = s;
  __syncthreads();
  if (t < 64) {
    float tot = red[t] + red[t + 64] + red[t + 128] + red[t + 192];
    inv[t] = 1.f / (1e-6f + sqrtf(tot));
  }
  __syncthreads();
  uint16_t* ob = basis + (size_t)b * C_ * K_;
  for (int i = 0; i < (C_ * K_) / 256; ++i) {
    int idx = t + 256 * i;
    int kk = idx & 63;
    ob[idx] = f2bf(bases[idx] * inv[kk]);
  }
  uint16_t* obT = basisT + (size_t)b * K_ * C_;
  for (int i = 0; i < (C_ * K_) / 256; ++i) {
    int idx = t + 256 * i;
    int kk = idx >> 9;
    int cc = idx & 511;
    obT[idx] = f2bf(bases[cc * K_ + kk] * inv[kk]);
  }
}

// ---------------- GEMM1 + fused softmax: attn[b,n,k] = softmax_k( sum_c fT[n,c]*basisT[k,c] )
// 128n x 64k, 512 threads, 2 c-phases of 256 (96 KB LDS), 2 barrier-pairs/block.
__global__ __launch_bounds__(512) void k_gemm1(const uint16_t* __restrict__ fT,
                                               const uint16_t* __restrict__ basisT,
                                               uint16_t* __restrict__ attn,    // [B][N][K]
                                               uint16_t* __restrict__ attnT,   // [B][K][N]
                                               int write_attn) {
  extern __shared__ __attribute__((aligned(16))) uint16_t lds[];
  uint16_t* ldsA = lds;                 // 128 rows x 256 c (swizzled 16B chunks)
  uint16_t* ldsB = lds + 128 * 256;     // 64 rows x 256 c
  int b = blockIdx.y;
  int n0 = blockIdx.x * 128;
  int t = threadIdx.x;
  int w = t >> 6, lane = t & 63, l15 = lane & 15, quad = lane >> 4;
  const uint16_t* A = fT + ((size_t)b * N_ + n0) * C_;
  const uint16_t* Bm = basisT + (size_t)b * K_ * C_;
  f32x4 acc[4] = {};
  for (int h = 0; h < 2; ++h) {
    int c0h = h * 256;
    __syncthreads();
#pragma unroll
    for (int i = 0; i < 8; ++i) {
      int e = i * 512 + t;
      int row = e >> 5, ch = e & 31;
      async16(A + (size_t)row * C_ + c0h + ((ch + row) & 31) * 8,
              ldsA + (i * 512 + (t & 448)) * 8);
    }
#pragma unroll
    for (int i = 0; i < 4; ++i) {
      int e = i * 512 + t;
      int row = e >> 5, ch = e & 31;
      async16(Bm + (size_t)row * C_ + c0h + ((ch + row) & 31) * 8,
              ldsB + (i * 512 + (t & 448)) * 8);
    }
    __syncthreads();
#pragma unroll
    for (int s = 0; s < 8; ++s) {
      int g = s * 4 + quad;
      int ra = 16 * w + l15;
      bf16x8 af = *(const bf16x8*)(ldsA + ((size_t)ra * 32 + ((g - ra) & 31)) * 8);
#pragma unroll
      for (int kt = 0; kt < 4; ++kt) {
        int rb = 16 * kt + l15;
        bf16x8 bv = *(const bf16x8*)(ldsB + ((size_t)rb * 32 + ((g - rb) & 31)) * 8);
        acc[kt] = __builtin_amdgcn_mfma_f32_16x16x32_bf16(af, bv, acc[kt], 0, 0, 0);
      }
    }
  }
  // fused softmax over k=64; row n = n0 + 16w + quad*4 + r, k = 16*kt + l15
  float p[4][4];
#pragma unroll
  for (int r = 0; r < 4; ++r) {
    float m = fmaxf(fmaxf(acc[0][r], acc[1][r]), fmaxf(acc[2][r], acc[3][r]));
    m = fmaxf(m, __shfl_xor(m, 1));
    m = fmaxf(m, __shfl_xor(m, 2));
    m = fmaxf(m, __shfl_xor(m, 4));
    m = fmaxf(m, __shfl_xor(m, 8));
    float s = 0.f;
#pragma unroll
    for (int kt = 0; kt < 4; ++kt) { p[kt][r] = __expf(acc[kt][r] - m); s += p[kt][r]; }
    s += __shfl_xor(s, 1); s += __shfl_xor(s, 2);
    s += __shfl_xor(s, 4); s += __shfl_xor(s, 8);
    float inv = 1.f / s;
#pragma unroll
    for (int kt = 0; kt < 4; ++kt) p[kt][r] *= inv;
  }
  if (write_attn) {
    uint16_t* oa = attn + ((size_t)b * N_ + n0 + 16 * w + quad * 4) * K_;
#pragma unroll
    for (int r = 0; r < 4; ++r) {
#pragma unroll
      for (int kt = 0; kt < 4; ++kt) oa[(size_t)r * K_ + 16 * kt + l15] = f2bf(p[kt][r]);
    }
  }
#pragma unroll
  for (int kt = 0; kt < 4; ++kt) {
    ushort4 y;
    y.x = f2bf(p[kt][0]); y.y = f2bf(p[kt][1]);
    y.z = f2bf(p[kt][2]); y.w = f2bf(p[kt][3]);
    *(ushort4*)(attnT + ((size_t)b * K_ + 16 * kt + l15) * N_ + n0 + 16 * w + quad * 4) = y;
  }
}

// ---------------- GEMM2 single-stage, split-K=16: braw[s][b][k][c] over 256-n slice
// 64k x 128c per block, 512 threads, 96 KB LDS, ONE barrier per block.
__global__ __launch_bounds__(512) void k_gemm2(const uint16_t* __restrict__ f16,
                                               const uint16_t* __restrict__ attnT,
                                               float* __restrict__ brawT) {
  extern __shared__ __attribute__((aligned(16))) uint16_t lds[];
  uint16_t* ldsF = lds;                 // 128 c-rows x 256 n
  uint16_t* ldsP = lds + 128 * 256;     // 64 k-rows x 256 n
  int b = blockIdx.z;
  int slice = blockIdx.y;
  int c0 = blockIdx.x * 128;
  int ns0 = slice * 256;
  int t = threadIdx.x;
  int w = t >> 6, lane = t & 63, l15 = lane & 15, quad = lane >> 4;
  const uint16_t* F = f16 + ((size_t)b * C_ + c0) * N_ + ns0;
  const uint16_t* P = attnT + (size_t)b * K_ * N_ + ns0;
#pragma unroll
  for (int i = 0; i < 8; ++i) {
    int e = i * 512 + t;
    int row = e >> 5, ch = e & 31;
    async16(F + (size_t)row * N_ + ((ch + row) & 31) * 8,
            ldsF + (i * 512 + (t & 448)) * 8);
  }
#pragma unroll
  for (int i = 0; i < 4; ++i) {
    int e = i * 512 + t;
    int row = e >> 5, ch = e & 31;
    async16(P + (size_t)row * N_ + ((ch + row) & 31) * 8,
            ldsP + (i * 512 + (t & 448)) * 8);
  }
  f32x4 acc[4] = {};
  __syncthreads();
#pragma unroll
  for (int s = 0; s < 8; ++s) {
    int g = s * 4 + quad;
    int rc = 16 * w + l15;
    bf16x8 fv = *(const bf16x8*)(ldsF + ((size_t)rc * 32 + ((g - rc) & 31)) * 8);
#pragma unroll
    for (int kt = 0; kt < 4; ++kt) {
      int ra = 16 * kt + l15;
      bf16x8 av = *(const bf16x8*)(ldsP + ((size_t)ra * 32 + ((g - ra) & 31)) * 8);
      acc[kt] = __builtin_amdgcn_mfma_f32_16x16x32_bf16(av, fv, acc[kt], 0, 0, 0);
    }
  }
  // D[m=k][col=c]: c = c0 + 16w + l15, k = 16kt + quad*4 + r
  float* outp = brawT + ((size_t)slice * B_ + b) * K_ * C_;
#pragma unroll
  for (int kt = 0; kt < 4; ++kt) {
#pragma unroll
    for (int r = 0; r < 4; ++r) {
      outp[(size_t)(16 * kt + quad * 4 + r) * C_ + c0 + 16 * w + l15] = acc[kt][r];
    }
  }
}

// ---------------- l2norm of b columns (over C), sum 16 slices; writes basisT AND basis
__global__ __launch_bounds__(256) void k_l2norm(const float* __restrict__ brawT,
                                                uint16_t* __restrict__ basisT,
                                                uint16_t* __restrict__ basis) {
  int b = blockIdx.x, kg = blockIdx.y;
  int t = threadIdx.x, w = t >> 6, lane = t & 63;
  int k = kg * 4 + w;
  float v[8];
#pragma unroll
  for (int j = 0; j < 8; ++j) v[j] = 0.f;
#pragma unroll
  for (int s = 0; s < 16; ++s) {
    const float* rs = brawT + (((size_t)s * B_ + b) * K_ + k) * C_ + lane * 8;
    float4 a = *(const float4*)(rs);
    float4 c4 = *(const float4*)(rs + 4);
    v[0] += a.x; v[1] += a.y; v[2] += a.z; v[3] += a.w;
    v[4] += c4.x; v[5] += c4.y; v[6] += c4.z; v[7] += c4.w;
  }
  float ss = 0.f;
#pragma unroll
  for (int j = 0; j < 8; ++j) ss += v[j] * v[j];
  ss += __shfl_xor(ss, 1); ss += __shfl_xor(ss, 2); ss += __shfl_xor(ss, 4);
  ss += __shfl_xor(ss, 8); ss += __shfl_xor(ss, 16); ss += __shfl_xor(ss, 32);
  float inv = 1.f / (1e-6f + sqrtf(ss));
  uint16_t y[8];
#pragma unroll
  for (int j = 0; j < 8; ++j) y[j] = f2bf(v[j] * inv);
  uint16_t* o = basisT + ((size_t)b * K_ + k) * C_ + lane * 8;
  *(ushort4*)(o) = *(ushort4*)&y[0];
  *(ushort4*)(o + 4) = *(ushort4*)&y[4];
  uint16_t* ob = basis + (size_t)b * C_ * K_ + k;
#pragma unroll
  for (int j = 0; j < 8; ++j) ob[(size_t)(lane * 8 + j) * K_] = y[j];
}

// ---------------- recon: out[b,c,n] = sum_k basis[c,k]*attn[n,k] (fp32 out)
// 128n x 64c per block, 512 threads, single stage.
__global__ __launch_bounds__(512) void k_recon(const uint16_t* __restrict__ attn,
                                               const uint16_t* __restrict__ basis,
                                               float* __restrict__ out) {
  __shared__ __attribute__((aligned(16))) uint16_t ldsA[128 * 64]; // n-rows x k
  __shared__ __attribute__((aligned(16))) uint16_t ldsB[64 * 64];  // c-rows x k
  int b = blockIdx.z, c0 = blockIdx.y * 64, n0 = blockIdx.x * 128;
  int t = threadIdx.x, w = t >> 6, lane = t & 63, l15 = lane & 15, quad = lane >> 4;
  const uint16_t* A = attn + ((size_t)b * N_ + n0) * K_;
  const uint16_t* Bm = basis + ((size_t)b * C_ + c0) * K_;
#pragma unroll
  for (int r = 0; r < 2; ++r) {
    int e = r * 512 + t;
    int row = e >> 3, ch = e & 7, sch = (ch + row) & 7;
    async16(A + (size_t)row * K_ + sch * 8, ldsA + (r * 512 + (t & 448)) * 8);
  }
  {
    int row = t >> 3, ch = t & 7, sch = (ch + row) & 7;
    async16(Bm + (size_t)row * K_ + sch * 8, ldsB + (t & 448) * 8);
  }
  f32x4 acc[4] = {};
  __syncthreads();
#pragma unroll
  for (int s = 0; s < 2; ++s) {
    int cc = s * 4 + quad;
    int ra = 16 * w + l15;
    bf16x8 af = *(const bf16x8*)(ldsA + (ra * 8 + ((cc - ra) & 7)) * 8);
#pragma unroll
    for (int t4 = 0; t4 < 4; ++t4) {
      int rb = 16 * t4 + l15;
      bf16x8 bv = *(const bf16x8*)(ldsB + (rb * 8 + ((cc - rb) & 7)) * 8);
      acc[t4] = __builtin_amdgcn_mfma_f32_16x16x32_bf16(af, bv, acc[t4], 0, 0, 0);
    }
  }
#pragma unroll
  for (int t4 = 0; t4 < 4; ++t4) {
    int c = c0 + 16 * t4 + l15;
    float4 v = make_float4(acc[t4][0], acc[t4][1], acc[t4][2], acc[t4][3]);
    *(float4*)(out + ((size_t)b * C_ + c) * N_ + n0 + 16 * w + quad * 4) = v;
  }
}

extern "C" void kernel_launch(void* const* d_in, const int* in_sizes, int n_in,
                              void* d_out, int out_size, void* d_ws, size_t ws_size,
                              hipStream_t stream) {
  const float* feats = (const float*)d_in[0];
  const float* bases = (const float*)d_in[1];
  float* out = (float*)d_out;
  char* ws = (char*)d_ws;
  uint16_t* f16 = (uint16_t*)(ws);                         // 64 MB
  uint16_t* fT16 = (uint16_t*)(ws + 67108864);             // 64 MB
  uint16_t* attn = (uint16_t*)(ws + 134217728);            // 8 MB
  uint16_t* attnT = (uint16_t*)(ws + 142606336);           // 8 MB
  uint16_t* basis = (uint16_t*)(ws + 150994944);           // 1 MB
  uint16_t* basisT = (uint16_t*)(ws + 152043520);          // 1 MB
  float* brawT = (float*)(ws + 153092096);                 // 32 MB (16 slices)

  const int ldsBytes = (128 * 256 + 64 * 256) * 2;  // 96 KB
  (void)hipFuncSetAttribute((const void*)k_gemm1,
                            hipFuncAttributeMaxDynamicSharedMemorySize, ldsBytes);
  (void)hipFuncSetAttribute((const void*)k_gemm2,
                            hipFuncAttributeMaxDynamicSharedMemorySize, ldsBytes);

  k_prep<<<dim3(64, 8, 16), 256, 0, stream>>>(feats, f16, fT16);
  k_init_basis<<<16, 256, 0, stream>>>(bases, basis, basisT);
  for (int st = 0; st < NUM_STAGES; ++st) {
    k_gemm1<<<dim3(32, 16), 512, ldsBytes, stream>>>(fT16, basisT, attn, attnT,
                                                     st == NUM_STAGES - 1 ? 1 : 0);
    k_gemm2<<<dim3(4, 16, 16), 512, ldsBytes, stream>>>(f16, attnT, brawT);
    k_l2norm<<<dim3(16, 16), 256, 0, stream>>>(brawT, basisT, basis);
  }
  k_recon<<<dim3(32, 8, 16), 512, 0, stream>>>(attn, basis, out);
}